// Round 5
// baseline (174.618 us; speedup 1.0000x reference)
//
#include <hip/hip_runtime.h>

#define NTOK 4096
#define NBH  32
#define NF   1088   // features: 32 linear + 1024 quadratic + 1 const + 31 pad
#define NE   33     // stored G columns: 32 v-cols + 1 ones-col (denominator)
#define GE   48     // Gt row-count stride (rows 33..47 never written/used)

typedef _Float16 half_t;
typedef _Float16 half8 __attribute__((ext_vector_type(8)));
typedef _Float16 half4v __attribute__((ext_vector_type(4)));
typedef _Float16 half2v __attribute__((ext_vector_type(2)));
typedef float f32x4 __attribute__((ext_vector_type(4)));
typedef unsigned int u32;

#define MFMA16(A,B,C) __builtin_amdgcn_mfma_f32_16x16x32_f16((A),(B),(C),0,0,0)

// async 16B global->LDS: lds dst = wave-uniform base + lane*16
#define ASYNC_CP16(dst_lds, src_glb) \
    __builtin_amdgcn_global_load_lds( \
        (const __attribute__((address_space(1))) u32*)(const void*)(src_glb), \
        (__attribute__((address_space(3))) u32*)(void*)(dst_lds), 16, 0, 0)

static __device__ __forceinline__ half8 splat8(half_t x) {
    return (half8){x, x, x, x, x, x, x, x};
}

// ---------------------------------------------------------------------------
// T: transpose + fp32->fp16  k,v [bh][n][32] -> [bh][32][n]
// ---------------------------------------------------------------------------
__global__ __launch_bounds__(256)
void t_kernel(const float* __restrict__ kin, const float* __restrict__ vin,
              half_t* __restrict__ kTg, half_t* __restrict__ vTg)
{
    const int nb = blockIdx.x;     // 16 blocks of 256 n
    const int bh = blockIdx.y;
    const int t  = threadIdx.x;
    __shared__ __align__(16) half_t tile[32 * 272];
    const size_t inbase = ((size_t)bh * NTOK + nb * 256) * 32;

    for (int pass = 0; pass < 2; ++pass) {
        const float* src = pass ? vin : kin;
        half_t* dstg     = pass ? vTg : kTg;
        if (pass) __syncthreads();
        const float4* s4 = (const float4*)(src + inbase);
        #pragma unroll
        for (int r = 0; r < 8; ++r) {
            int f4 = t + 256 * r;
            int n = f4 >> 3, d4 = f4 & 7;
            float4 vv = s4[f4];
            int nn = n ^ ((d4 & 7) << 3);
            int d0 = d4 * 4;
            tile[(d0 + 0) * 272 + nn] = (half_t)vv.x;
            tile[(d0 + 1) * 272 + nn] = (half_t)vv.y;
            tile[(d0 + 2) * 272 + nn] = (half_t)vv.z;
            tile[(d0 + 3) * 272 + nn] = (half_t)vv.w;
        }
        __syncthreads();
        #pragma unroll
        for (int cc = 0; cc < 4; ++cc) {
            int lin = t + 256 * cc;
            int d = lin >> 5, ch = lin & 31;
            int sw = (d >> 2) & 7;
            half8 val = *(const half8*)&tile[d * 272 + ((ch ^ sw) << 3)];
            *(half8*)&dstg[((size_t)bh * 32 + d) * NTOK + nb * 256 + ch * 8] = val;
        }
    }
}

// ---------------------------------------------------------------------------
// A: G[p][e] = sum_n phi(k_n)[p] * [v_n | 1][e]  via f16 MFMA.
// A2=0.5 folded into the quadratic ki fragments (0.5*k exact in fp16).
// Partials stored fp16 (magnitudes ~1e2, rounding contributes <1e-4 to out).
// Staging: global_load_lds width=16 into chunk-XOR-swizzled [32][128] tiles.
// Grid: x = kc*NBH+bh (slice), y = mb -> slice-sharing blocks land same XCD.
// ---------------------------------------------------------------------------
__global__ __launch_bounds__(256)
void a_kernel(const half_t* __restrict__ kTg, const half_t* __restrict__ vTg,
              half_t* __restrict__ P, int Kc)
{
    const int x  = blockIdx.x;
    const int bh = x & (NBH - 1);
    const int kc = x >> 5;
    const int mb = blockIdx.y;   // 0..4 : 256 features each (mb4: only w0 real)
    const int t = threadIdx.x;
    const int w = t >> 6, lane = t & 63, l16 = lane & 15, quad = lane >> 4;

    __shared__ __align__(16) half_t kT[32 * 128];
    __shared__ __align__(16) half_t vT[32 * 128];

    const int pw = mb * 256 + w * 64;
    const bool active = (pw < NF);
    const int mode = (mb == 0 && w == 0) ? 1 : ((mb == 4) ? 2 : 0);
    const int i0 = (pw >= 32 && pw < NF) ? ((pw - 32) >> 5) : 0;
    const half8 h05 = splat8((half_t)0.5f);

    f32x4 acc[3][4];
    #pragma unroll
    for (int a = 0; a < 3; ++a)
        #pragma unroll
        for (int b = 0; b < 4; ++b)
            acc[a][b] = (f32x4){0.f, 0.f, 0.f, 0.f};

    const size_t gbase = (size_t)bh * 32 * NTOK;
    const int nPer = NTOK / Kc;
    const int nStages = nPer >> 7;

    // per-thread staging source (row, part) for the 2 issues
    const int c0 = t,        r0 = c0 >> 4, p0s = (c0 & 15) ^ (r0 & 15);
    const int c1 = 256 + t,  r1 = c1 >> 4, p1s = (c1 & 15) ^ (r1 & 15);

    for (int st = 0; st < nStages; ++st) {
        __syncthreads();
        const int nbase = kc * nPer + st * 128;
        {
            const half_t* gk0 = kTg + gbase + (size_t)r0 * NTOK + nbase + p0s * 8;
            const half_t* gk1 = kTg + gbase + (size_t)r1 * NTOK + nbase + p1s * 8;
            const half_t* gv0 = vTg + gbase + (size_t)r0 * NTOK + nbase + p0s * 8;
            const half_t* gv1 = vTg + gbase + (size_t)r1 * NTOK + nbase + p1s * 8;
            ASYNC_CP16(kT + (size_t)w * 512,        gk0);
            ASYNC_CP16(kT + 2048 + (size_t)w * 512, gk1);
            ASYNC_CP16(vT + (size_t)w * 512,        gv0);
            ASYNC_CP16(vT + 2048 + (size_t)w * 512, gv1);
        }
        __syncthreads();
        if (!active) continue;
        #pragma unroll
        for (int kk = 0; kk < 4; ++kk) {
            const int c = kk * 4 + quad;               // logical chunk col
            const int offL = l16 * 128 + ((c ^ l16) << 3);
            const int offH = (l16 + 16) * 128 + ((c ^ l16) << 3);
            half8 bf0 = *(const half8*)&vT[offL];
            half8 bf1 = *(const half8*)&vT[offH];
            half_t onec = (l16 == 0) ? (half_t)1 : (half_t)0;
            half8 bf2 = {onec, onec, onec, onec, onec, onec, onec, onec};
            half8 kj0 = *(const half8*)&kT[offL];
            half8 kj1 = *(const half8*)&kT[offH];
            half8 af[4];
            bool skip3 = false;
            if (mode == 1) {            // p 0..63: linear tiles + i=0 quads
                half8 ki = *(const half8*)&kT[(c ^ 0) << 3];
                ki = ki * h05;
                af[0] = kj0; af[1] = kj1;
                af[2] = ki * kj0; af[3] = ki * kj1;
            } else if (mode == 2) {     // p 1024..1087: i=31, const, skip
                half8 ki = *(const half8*)&kT[31 * 128 + ((c ^ 15) << 3)];
                ki = ki * h05;
                af[0] = ki * kj0; af[1] = ki * kj1;
                af[2] = bf2;            // const feature row 1056 (l16==0)
                af[3] = bf2;
                skip3 = true;
            } else {
                half8 kia = *(const half8*)&kT[i0 * 128 + ((c ^ (i0 & 15)) << 3)];
                half8 kib = *(const half8*)&kT[(i0 + 1) * 128 + ((c ^ ((i0 + 1) & 15)) << 3)];
                kia = kia * h05;
                kib = kib * h05;
                af[0] = kia * kj0; af[1] = kia * kj1;
                af[2] = kib * kj0; af[3] = kib * kj1;
            }
            #pragma unroll
            for (int mt = 0; mt < 4; ++mt) {
                if (skip3 && mt == 3) continue;
                acc[0][mt] = MFMA16(af[mt], bf0, acc[0][mt]);
                acc[1][mt] = MFMA16(af[mt], bf1, acc[1][mt]);
                acc[2][mt] = MFMA16(af[mt], bf2, acc[2][mt]);
            }
        }
    }
    if (active) {
        half_t* Pb = P + ((size_t)kc * NBH + bh) * NE * NF;
        #pragma unroll
        for (int mt = 0; mt < 4; ++mt) {
            int p0 = pw + mt * 16 + quad * 4;
            half4v h0 = {(half_t)acc[0][mt][0], (half_t)acc[0][mt][1],
                         (half_t)acc[0][mt][2], (half_t)acc[0][mt][3]};
            half4v h1 = {(half_t)acc[1][mt][0], (half_t)acc[1][mt][1],
                         (half_t)acc[1][mt][2], (half_t)acc[1][mt][3]};
            *(half4v*)&Pb[(size_t)l16 * NF + p0] = h0;
            *(half4v*)&Pb[(size_t)(l16 + 16) * NF + p0] = h1;
            if (l16 == 0) {
                half4v h2 = {(half_t)acc[2][mt][0], (half_t)acc[2][mt][1],
                             (half_t)acc[2][mt][2], (half_t)acc[2][mt][3]};
                *(half4v*)&Pb[(size_t)32 * NF + p0] = h2;
            }
        }
    }
}

// ---------------------------------------------------------------------------
// AR: sum Kc fp16 partial planes (fp32 accum) -> fp16 Gt (0.5 already folded)
// ---------------------------------------------------------------------------
__global__ __launch_bounds__(256)
void ar_kernel(const half_t* __restrict__ P, half_t* __restrict__ Gt, int Kc)
{
    const int NP8 = NBH * NE * NF / 8;   // 143616
    const int idx = blockIdx.x * 256 + threadIdx.x;
    if (idx >= NP8) return;
    float s[8] = {0.f, 0.f, 0.f, 0.f, 0.f, 0.f, 0.f, 0.f};
    for (int c = 0; c < Kc; ++c) {
        half8 h = *(const half8*)&P[(size_t)c * (NBH * NE * NF) + (size_t)idx * 8];
        #pragma unroll
        for (int j = 0; j < 8; ++j) s[j] += (float)h[j];
    }
    half8 o;
    #pragma unroll
    for (int j = 0; j < 8; ++j) o[j] = (half_t)s[j];
    int row = idx / 136;                 // NF/8
    int p8 = idx - row * 136;
    int e = row % 33, bhh = row / 33;
    *(half8*)&Gt[((size_t)(bhh * GE + e)) * NF + p8 * 8] = o;
}

// ---------------------------------------------------------------------------
// B: out[n][e] = (phi(q_n).G[:,e]) / (phi(q_n).G[:,32]) via f16 MFMA.
// 128 queries/block (1024 blocks = 4/CU) for latency hiding. Per-mt scalars
// via one ds_read_b32 (half2) from qsP[i][w][l16][mt]. Gt B-frags streamed
// from global (L2) with depth-2 prefetch ring.
// ---------------------------------------------------------------------------
__global__ __launch_bounds__(256)
void b_kernel(const float* __restrict__ qin, const half_t* __restrict__ Gt,
              float* __restrict__ out)
{
    const int bh = blockIdx.x, mbq = blockIdx.y;   // 32 x 32
    const int t = threadIdx.x, w = t >> 6, lane = t & 63;
    const int l16 = lane & 15, quad = lane >> 4;
    __shared__ __align__(16) half_t qs[128 * 40];   // row-major padded
    __shared__ __align__(16) half_t qsP[32 * 136];  // [i][w][l16][mt]
    __shared__ float denl[128];
    const size_t nbase = (size_t)bh * NTOK + mbq * 128;

    const float4* q4 = (const float4*)(qin + nbase * 32);
    #pragma unroll
    for (int r = 0; r < 4; ++r) {
        int f4 = t + 256 * r, n = f4 >> 3, d4 = f4 & 7;
        float4 vv = q4[f4];
        half4v h = {(half_t)vv.x, (half_t)vv.y, (half_t)vv.z, (half_t)vv.w};
        *(half4v*)&qs[n * 40 + d4 * 4] = h;
        int pb = (n >> 5) * 32 + (n & 15) * 2 + ((n >> 4) & 1);
        qsP[(4 * d4 + 0) * 136 + pb] = h[0];
        qsP[(4 * d4 + 1) * 136 + pb] = h[1];
        qsP[(4 * d4 + 2) * 136 + pb] = h[2];
        qsP[(4 * d4 + 3) * 136 + pb] = h[3];
    }
    __syncthreads();

    const int rbase = w * 32;
    half8 vq[2];
    #pragma unroll
    for (int mt = 0; mt < 2; ++mt)
        vq[mt] = *(const half8*)&qs[(rbase + mt * 16 + l16) * 40 + quad * 8];

    f32x4 acc[3][2];
    #pragma unroll
    for (int a = 0; a < 3; ++a)
        #pragma unroll
        for (int b = 0; b < 2; ++b)
            acc[a][b] = (f32x4){0.f, 0.f, 0.f, 0.f};

    const half_t* Gb = Gt + (size_t)bh * GE * NF;
    const int koff = quad * 8;
    const int sOff = w * 32 + l16 * 2;

    half8 B0[3], B1[3], B2[3];
    #pragma unroll
    for (int rr = 0; rr < 3; ++rr) {
        B0[rr] = *(const half8*)&Gb[(size_t)(l16 + 16 * rr) * NF + koff];
        B1[rr] = *(const half8*)&Gb[(size_t)(l16 + 16 * rr) * NF + 32 + koff];
    }

    #pragma unroll 1
    for (int kt = 0; kt <= 32; ++kt) {
        const int ktn = (kt + 2 <= 32) ? kt + 2 : 32;
        const int o = ktn * 32 + koff;
        #pragma unroll
        for (int rr = 0; rr < 3; ++rr)
            B2[rr] = *(const half8*)&Gb[(size_t)(l16 + 16 * rr) * NF + o];

        half8 af[2];
        if (kt == 0) {                   // linear features: phi = q_j
            af[0] = vq[0]; af[1] = vq[1];
        } else {                         // quadratic: phi = q_i * q_j
            half2v sv = *(const half2v*)&qsP[(kt - 1) * 136 + sOff];
            af[0] = vq[0] * splat8(sv[0]);
            af[1] = vq[1] * splat8(sv[1]);
        }
        #pragma unroll
        for (int mt = 0; mt < 2; ++mt) {
            acc[0][mt] = MFMA16(af[mt], B0[0], acc[0][mt]);
            acc[1][mt] = MFMA16(af[mt], B0[1], acc[1][mt]);
            acc[2][mt] = MFMA16(af[mt], B0[2], acc[2][mt]);
        }
        #pragma unroll
        for (int rr = 0; rr < 3; ++rr) { B0[rr] = B1[rr]; B1[rr] = B2[rr]; }
    }
    // constant feature row p=1056: adds v0[e] to num, 4096 to den
    float g0 = (float)Gb[(size_t)l16 * NF + 1056];
    float g1 = (float)Gb[(size_t)(l16 + 16) * NF + 1056];
    float g2 = (float)Gb[(size_t)(l16 + 32) * NF + 1056];
    #pragma unroll
    for (int mt = 0; mt < 2; ++mt)
        #pragma unroll
        for (int r = 0; r < 4; ++r) {
            acc[0][mt][r] += g0; acc[1][mt][r] += g1; acc[2][mt][r] += g2;
        }
    // broadcast den (col 32 lives in l16==0 lanes) via LDS
    if (l16 == 0) {
        #pragma unroll
        for (int mt = 0; mt < 2; ++mt)
            #pragma unroll
            for (int r = 0; r < 4; ++r)
                denl[rbase + mt * 16 + quad * 4 + r] = acc[2][mt][r];
    }
    __syncthreads();
    #pragma unroll
    for (int mt = 0; mt < 2; ++mt) {
        float inv[4];
        #pragma unroll
        for (int r = 0; r < 4; ++r)
            inv[r] = __builtin_amdgcn_rcpf(denl[rbase + mt * 16 + quad * 4 + r]);
        #pragma unroll
        for (int r = 0; r < 4; ++r) {
            size_t ro = (nbase + rbase + mt * 16 + quad * 4 + r) * 32;
            out[ro + l16] = acc[0][mt][r] * inv[r];
            out[ro + l16 + 16] = acc[1][mt][r] * inv[r];
        }
    }
}

// ---------------------------------------------------------------------------
extern "C" void kernel_launch(void* const* d_in, const int* in_sizes, int n_in,
                              void* d_out, int out_size, void* d_ws, size_t ws_size,
                              hipStream_t stream)
{
    const float* q = (const float*)d_in[0];
    const float* k = (const float*)d_in[1];
    const float* v = (const float*)d_in[2];
    float* out = (float*)d_out;

    const size_t planeBytes = (size_t)NBH * NE * NF * 2;   // fp16: 2,297,856
    const size_t ktBytes = (size_t)NBH * 32 * NTOK * 2;    // 8,388,608
    const size_t gtBytes = (size_t)NBH * GE * NF * 2;      // 3,342,336
    int Kc = 8;
    while (Kc > 1 && ((size_t)Kc * planeBytes + 2 * ktBytes + gtBytes) > ws_size)
        Kc >>= 1;

    half_t* P = (half_t*)d_ws;
    half_t* kTg = (half_t*)((char*)d_ws + (size_t)Kc * planeBytes);
    half_t* vTg = kTg + (size_t)NBH * 32 * NTOK;
    half_t* Gt = vTg + (size_t)NBH * 32 * NTOK;

    t_kernel<<<dim3(16, NBH), 256, 0, stream>>>(k, v, kTg, vTg);
    a_kernel<<<dim3(Kc * NBH, 5), 256, 0, stream>>>(kTg, vTg, P, Kc);
    ar_kernel<<<561, 256, 0, stream>>>(P, Gt, Kc);
    b_kernel<<<dim3(NBH, 32), 256, 0, stream>>>(q, Gt, out);
}

// Round 6
// 142.340 us; speedup vs baseline: 1.2268x; 1.2268x over previous
//
#include <hip/hip_runtime.h>

#define NTOK 4096
#define NBH  32
#define NF   1088   // features: 32 linear + 1024 quadratic + 1 const + 31 pad
#define NE   33     // stored G columns: 32 v-cols + 1 ones-col (denominator)
#define GTF_BH 52224  // per-bh GtF halves: 34 kt * 3 rr * 64 lanes * 8

typedef _Float16 half_t;
typedef _Float16 half8 __attribute__((ext_vector_type(8)));
typedef _Float16 half4v __attribute__((ext_vector_type(4)));
typedef float f32x4 __attribute__((ext_vector_type(4)));
typedef unsigned int u32;

#define MFMA16(A,B,C) __builtin_amdgcn_mfma_f32_16x16x32_f16((A),(B),(C),0,0,0)

// async 16B global->LDS: lds dst = wave-uniform base + lane*16
#define ASYNC_CP16(dst_lds, src_glb) \
    __builtin_amdgcn_global_load_lds( \
        (const __attribute__((address_space(1))) u32*)(const void*)(src_glb), \
        (__attribute__((address_space(3))) u32*)(void*)(dst_lds), 16, 0, 0)

static __device__ __forceinline__ half8 splat8(half_t x) {
    return (half8){x, x, x, x, x, x, x, x};
}

// ---------------------------------------------------------------------------
// T: transpose + fp32->fp16  k,v [bh][n][32] -> [bh][32][n]
// ---------------------------------------------------------------------------
__global__ __launch_bounds__(256)
void t_kernel(const float* __restrict__ kin, const float* __restrict__ vin,
              half_t* __restrict__ kTg, half_t* __restrict__ vTg)
{
    const int nb = blockIdx.x;     // 16 blocks of 256 n
    const int bh = blockIdx.y;
    const int t  = threadIdx.x;
    __shared__ __align__(16) half_t tile[32 * 272];
    const size_t inbase = ((size_t)bh * NTOK + nb * 256) * 32;

    for (int pass = 0; pass < 2; ++pass) {
        const float* src = pass ? vin : kin;
        half_t* dstg     = pass ? vTg : kTg;
        if (pass) __syncthreads();
        const float4* s4 = (const float4*)(src + inbase);
        #pragma unroll
        for (int r = 0; r < 8; ++r) {
            int f4 = t + 256 * r;
            int n = f4 >> 3, d4 = f4 & 7;
            float4 vv = s4[f4];
            int nn = n ^ ((d4 & 7) << 3);
            int d0 = d4 * 4;
            tile[(d0 + 0) * 272 + nn] = (half_t)vv.x;
            tile[(d0 + 1) * 272 + nn] = (half_t)vv.y;
            tile[(d0 + 2) * 272 + nn] = (half_t)vv.z;
            tile[(d0 + 3) * 272 + nn] = (half_t)vv.w;
        }
        __syncthreads();
        #pragma unroll
        for (int cc = 0; cc < 4; ++cc) {
            int lin = t + 256 * cc;
            int d = lin >> 5, ch = lin & 31;
            int sw = (d >> 2) & 7;
            half8 val = *(const half8*)&tile[d * 272 + ((ch ^ sw) << 3)];
            *(half8*)&dstg[((size_t)bh * 32 + d) * NTOK + nb * 256 + ch * 8] = val;
        }
    }
}

// ---------------------------------------------------------------------------
// A: G[p][e] = sum_n phi(k_n)[p] * [v_n | 1][e]  via f16 MFMA.
// A2=0.5 folded into quadratic ki fragments. Partials fp16.
// Staging: global_load_lds width=16 into chunk-XOR-swizzled [32][128] tiles.
// ---------------------------------------------------------------------------
__global__ __launch_bounds__(256)
void a_kernel(const half_t* __restrict__ kTg, const half_t* __restrict__ vTg,
              half_t* __restrict__ P, int Kc)
{
    const int x  = blockIdx.x;
    const int bh = x & (NBH - 1);
    const int kc = x >> 5;
    const int mb = blockIdx.y;   // 0..4 : 256 features each (mb4: only w0 real)
    const int t = threadIdx.x;
    const int w = t >> 6, lane = t & 63, l16 = lane & 15, quad = lane >> 4;

    __shared__ __align__(16) half_t kT[32 * 128];
    __shared__ __align__(16) half_t vT[32 * 128];

    const int pw = mb * 256 + w * 64;
    const bool active = (pw < NF);
    const int mode = (mb == 0 && w == 0) ? 1 : ((mb == 4) ? 2 : 0);
    const int i0 = (pw >= 32 && pw < NF) ? ((pw - 32) >> 5) : 0;
    const half8 h05 = splat8((half_t)0.5f);

    f32x4 acc[3][4];
    #pragma unroll
    for (int a = 0; a < 3; ++a)
        #pragma unroll
        for (int b = 0; b < 4; ++b)
            acc[a][b] = (f32x4){0.f, 0.f, 0.f, 0.f};

    const size_t gbase = (size_t)bh * 32 * NTOK;
    const int nPer = NTOK / Kc;
    const int nStages = nPer >> 7;

    const int c0 = t,        r0 = c0 >> 4, p0s = (c0 & 15) ^ (r0 & 15);
    const int c1 = 256 + t,  r1 = c1 >> 4, p1s = (c1 & 15) ^ (r1 & 15);

    for (int st = 0; st < nStages; ++st) {
        __syncthreads();
        const int nbase = kc * nPer + st * 128;
        {
            const half_t* gk0 = kTg + gbase + (size_t)r0 * NTOK + nbase + p0s * 8;
            const half_t* gk1 = kTg + gbase + (size_t)r1 * NTOK + nbase + p1s * 8;
            const half_t* gv0 = vTg + gbase + (size_t)r0 * NTOK + nbase + p0s * 8;
            const half_t* gv1 = vTg + gbase + (size_t)r1 * NTOK + nbase + p1s * 8;
            ASYNC_CP16(kT + (size_t)w * 512,        gk0);
            ASYNC_CP16(kT + 2048 + (size_t)w * 512, gk1);
            ASYNC_CP16(vT + (size_t)w * 512,        gv0);
            ASYNC_CP16(vT + 2048 + (size_t)w * 512, gv1);
        }
        __syncthreads();
        if (!active) continue;
        #pragma unroll
        for (int kk = 0; kk < 4; ++kk) {
            const int c = kk * 4 + quad;
            const int offL = l16 * 128 + ((c ^ l16) << 3);
            const int offH = (l16 + 16) * 128 + ((c ^ l16) << 3);
            half8 bf0 = *(const half8*)&vT[offL];
            half8 bf1 = *(const half8*)&vT[offH];
            half_t onec = (l16 == 0) ? (half_t)1 : (half_t)0;
            half8 bf2 = {onec, onec, onec, onec, onec, onec, onec, onec};
            half8 kj0 = *(const half8*)&kT[offL];
            half8 kj1 = *(const half8*)&kT[offH];
            half8 af[4];
            bool skip3 = false;
            if (mode == 1) {
                half8 ki = *(const half8*)&kT[(c ^ 0) << 3];
                ki = ki * h05;
                af[0] = kj0; af[1] = kj1;
                af[2] = ki * kj0; af[3] = ki * kj1;
            } else if (mode == 2) {
                half8 ki = *(const half8*)&kT[31 * 128 + ((c ^ 15) << 3)];
                ki = ki * h05;
                af[0] = ki * kj0; af[1] = ki * kj1;
                af[2] = bf2;
                af[3] = bf2;
                skip3 = true;
            } else {
                half8 kia = *(const half8*)&kT[i0 * 128 + ((c ^ (i0 & 15)) << 3)];
                half8 kib = *(const half8*)&kT[(i0 + 1) * 128 + ((c ^ ((i0 + 1) & 15)) << 3)];
                kia = kia * h05;
                kib = kib * h05;
                af[0] = kia * kj0; af[1] = kia * kj1;
                af[2] = kib * kj0; af[3] = kib * kj1;
            }
            #pragma unroll
            for (int mt = 0; mt < 4; ++mt) {
                if (skip3 && mt == 3) continue;
                acc[0][mt] = MFMA16(af[mt], bf0, acc[0][mt]);
                acc[1][mt] = MFMA16(af[mt], bf1, acc[1][mt]);
                acc[2][mt] = MFMA16(af[mt], bf2, acc[2][mt]);
            }
        }
    }
    if (active) {
        half_t* Pb = P + ((size_t)kc * NBH + bh) * NE * NF;
        #pragma unroll
        for (int mt = 0; mt < 4; ++mt) {
            int p0 = pw + mt * 16 + quad * 4;
            half4v h0 = {(half_t)acc[0][mt][0], (half_t)acc[0][mt][1],
                         (half_t)acc[0][mt][2], (half_t)acc[0][mt][3]};
            half4v h1 = {(half_t)acc[1][mt][0], (half_t)acc[1][mt][1],
                         (half_t)acc[1][mt][2], (half_t)acc[1][mt][3]};
            *(half4v*)&Pb[(size_t)l16 * NF + p0] = h0;
            *(half4v*)&Pb[(size_t)(l16 + 16) * NF + p0] = h1;
            if (l16 == 0) {
                half4v h2 = {(half_t)acc[2][mt][0], (half_t)acc[2][mt][1],
                             (half_t)acc[2][mt][2], (half_t)acc[2][mt][3]};
                *(half4v*)&Pb[(size_t)32 * NF + p0] = h2;
            }
        }
    }
}

// ---------------------------------------------------------------------------
// AR: sum Kc fp16 partial planes (fp32 accum) -> GtF in MFMA-B-FRAGMENT order:
//   GtF[bh][kt(34)][rr(3)][lane=quad*16+l16][j(8)]
//   element (p,e): kt=p>>5, quad=(p>>3)&3, j=p&7, rr=e>>4(e=32->rr=2,l16=0)
// b_kernel's per-(kt,rr) fragment load becomes one dense 1KB wave load.
// ---------------------------------------------------------------------------
__global__ __launch_bounds__(256)
void ar_kernel(const half_t* __restrict__ P, half_t* __restrict__ GtF, int Kc)
{
    const int NP8 = NBH * NE * NF / 8;   // 143616
    const int idx = blockIdx.x * 256 + threadIdx.x;
    if (idx >= NP8) return;
    float s[8] = {0.f, 0.f, 0.f, 0.f, 0.f, 0.f, 0.f, 0.f};
    for (int c = 0; c < Kc; ++c) {
        half8 h = *(const half8*)&P[(size_t)c * (NBH * NE * NF) + (size_t)idx * 8];
        #pragma unroll
        for (int j = 0; j < 8; ++j) s[j] += (float)h[j];
    }
    half8 o;
    #pragma unroll
    for (int j = 0; j < 8; ++j) o[j] = (half_t)s[j];
    int row = idx / 136;                 // NF/8
    int p8 = idx - row * 136;
    int e = row % 33, bhh = row / 33;
    int kt = p8 >> 2, quad = p8 & 3;
    int rr = e >> 4, l16 = e & 15;       // e==32 -> rr=2, l16=0
    size_t dst8 = (size_t)bhh * (GTF_BH / 8)
                + (size_t)(kt * 3 + rr) * 64 + quad * 16 + l16;
    *(half8*)&GtF[dst8 * 8] = o;
}

// ---------------------------------------------------------------------------
// B: out[n][e] = (phi(q_n).G[:,e]) / (phi(q_n).G[:,32]) via f16 MFMA.
// 256 q/block, 512 blocks. GtF fragments are lane-dense (1KB/wave/load),
// streamed with a depth-3 register ring. kt=33 carries the const feature
// (af = e_0 on quad 0) -> no scalar epilogue.
// ---------------------------------------------------------------------------
__global__ __launch_bounds__(256)
void b_kernel(const float* __restrict__ qin, const half_t* __restrict__ GtF,
              float* __restrict__ out)
{
    const int bh = blockIdx.x, mbq = blockIdx.y;   // 32 x 16
    const int t = threadIdx.x, w = t >> 6, lane = t & 63;
    const int l16 = lane & 15, quad = lane >> 4;
    __shared__ __align__(16) half_t qs[256 * 40];
    __shared__ __align__(16) half_t qsP[32 * 272];  // [i][w][l16][mt]
    __shared__ float denl[256];
    const size_t nbase = (size_t)bh * NTOK + mbq * 256;

    const float4* q4 = (const float4*)(qin + nbase * 32);
    #pragma unroll
    for (int r = 0; r < 8; ++r) {
        int f4 = t + 256 * r, n = f4 >> 3, d4 = f4 & 7;
        float4 vv = q4[f4];
        half4v h = {(half_t)vv.x, (half_t)vv.y, (half_t)vv.z, (half_t)vv.w};
        *(half4v*)&qs[n * 40 + d4 * 4] = h;
        int pb = (n >> 6) * 64 + (n & 15) * 4 + ((n >> 4) & 3);
        qsP[(4 * d4 + 0) * 272 + pb] = h[0];
        qsP[(4 * d4 + 1) * 272 + pb] = h[1];
        qsP[(4 * d4 + 2) * 272 + pb] = h[2];
        qsP[(4 * d4 + 3) * 272 + pb] = h[3];
    }
    __syncthreads();

    const int rbase = w * 64;
    half8 vq[4];
    #pragma unroll
    for (int mt = 0; mt < 4; ++mt)
        vq[mt] = *(const half8*)&qs[(rbase + mt * 16 + l16) * 40 + quad * 8];

    f32x4 acc[3][4];
    #pragma unroll
    for (int a = 0; a < 3; ++a)
        #pragma unroll
        for (int b = 0; b < 4; ++b)
            acc[a][b] = (f32x4){0.f, 0.f, 0.f, 0.f};

    const half_t* Gb = GtF + (size_t)bh * GTF_BH + (size_t)lane * 8;
    const int sOff = w * 64 + l16 * 4;

#define LDF(kt, B) do { \
    _Pragma("unroll") \
    for (int rr = 0; rr < 3; ++rr) \
        (B)[rr] = *(const half8*)&Gb[(size_t)(((kt) * 3 + rr) * 64) * 8]; \
} while (0)

    half8 B0[3], B1[3], B2[3], B3[3];
    LDF(0, B0); LDF(1, B1); LDF(2, B2);

    // kt = 0: linear features, af = vq
    {
        LDF(3, B3);
        #pragma unroll
        for (int mt = 0; mt < 4; ++mt) {
            acc[0][mt] = MFMA16(vq[mt], B0[0], acc[0][mt]);
            acc[1][mt] = MFMA16(vq[mt], B0[1], acc[1][mt]);
            acc[2][mt] = MFMA16(vq[mt], B0[2], acc[2][mt]);
        }
        #pragma unroll
        for (int rr = 0; rr < 3; ++rr) { B0[rr] = B1[rr]; B1[rr] = B2[rr]; B2[rr] = B3[rr]; }
    }
    // kt = 1..32: quadratic features, af = q_i * vq
    #pragma unroll 1
    for (int kt = 1; kt <= 32; ++kt) {
        const int ktp = (kt + 3 <= 33) ? kt + 3 : 33;
        LDF(ktp, B3);
        half4v sv = *(const half4v*)&qsP[(kt - 1) * 272 + sOff];
        half8 af[4];
        #pragma unroll
        for (int mt = 0; mt < 4; ++mt)
            af[mt] = vq[mt] * splat8(sv[mt]);
        #pragma unroll
        for (int mt = 0; mt < 4; ++mt) {
            acc[0][mt] = MFMA16(af[mt], B0[0], acc[0][mt]);
            acc[1][mt] = MFMA16(af[mt], B0[1], acc[1][mt]);
            acc[2][mt] = MFMA16(af[mt], B0[2], acc[2][mt]);
        }
        #pragma unroll
        for (int rr = 0; rr < 3; ++rr) { B0[rr] = B1[rr]; B1[rr] = B2[rr]; B2[rr] = B3[rr]; }
    }
    // kt = 33: const feature at p=1056 (k=0 of this tile): af = e0 on quad 0
    {
        half8 cf = {};
        if (quad == 0) cf[0] = (half_t)1;
        #pragma unroll
        for (int mt = 0; mt < 4; ++mt) {
            acc[0][mt] = MFMA16(cf, B0[0], acc[0][mt]);
            acc[1][mt] = MFMA16(cf, B0[1], acc[1][mt]);
            acc[2][mt] = MFMA16(cf, B0[2], acc[2][mt]);
        }
    }
#undef LDF

    // broadcast den (col 32 lives in l16==0 lanes of acc[2]) via LDS
    if (l16 == 0) {
        #pragma unroll
        for (int mt = 0; mt < 4; ++mt)
            #pragma unroll
            for (int r = 0; r < 4; ++r)
                denl[rbase + mt * 16 + quad * 4 + r] = acc[2][mt][r];
    }
    __syncthreads();
    #pragma unroll
    for (int mt = 0; mt < 4; ++mt) {
        float inv[4];
        #pragma unroll
        for (int r = 0; r < 4; ++r)
            inv[r] = __builtin_amdgcn_rcpf(denl[rbase + mt * 16 + quad * 4 + r]);
        #pragma unroll
        for (int r = 0; r < 4; ++r) {
            size_t ro = (nbase + rbase + mt * 16 + quad * 4 + r) * 32;
            out[ro + l16] = acc[0][mt][r] * inv[r];
            out[ro + l16 + 16] = acc[1][mt][r] * inv[r];
        }
    }
}

// ---------------------------------------------------------------------------
extern "C" void kernel_launch(void* const* d_in, const int* in_sizes, int n_in,
                              void* d_out, int out_size, void* d_ws, size_t ws_size,
                              hipStream_t stream)
{
    const float* q = (const float*)d_in[0];
    const float* k = (const float*)d_in[1];
    const float* v = (const float*)d_in[2];
    float* out = (float*)d_out;

    const size_t planeBytes = (size_t)NBH * NE * NF * 2;   // fp16: 2,297,856
    const size_t ktBytes = (size_t)NBH * 32 * NTOK * 2;    // 8,388,608
    const size_t gtBytes = (size_t)NBH * GTF_BH * 2;       // 3,342,336
    int Kc = 8;
    while (Kc > 1 && ((size_t)Kc * planeBytes + 2 * ktBytes + gtBytes) > ws_size)
        Kc >>= 1;

    half_t* P = (half_t*)d_ws;
    half_t* kTg = (half_t*)((char*)d_ws + (size_t)Kc * planeBytes);
    half_t* vTg = kTg + (size_t)NBH * 32 * NTOK;
    half_t* GtF = vTg + (size_t)NBH * 32 * NTOK;

    t_kernel<<<dim3(16, NBH), 256, 0, stream>>>(k, v, kTg, vTg);
    a_kernel<<<dim3(Kc * NBH, 5), 256, 0, stream>>>(kTg, vTg, P, Kc);
    ar_kernel<<<561, 256, 0, stream>>>(P, GtF, Kc);
    b_kernel<<<dim3(NBH, 16), 256, 0, stream>>>(q, GtF, out);
}

// Round 7
// 137.906 us; speedup vs baseline: 1.2662x; 1.0322x over previous
//
#include <hip/hip_runtime.h>

#define NTOK 4096
#define NBH  32
#define NF   1088   // features: 32 linear + 1024 quadratic + 1 const + 31 pad
#define NE   33     // stored G columns: 32 v-cols + 1 ones-col (denominator)
#define GTF_BH 52224  // per-bh GtF halves: 34 kt * 3 rr * 64 lanes * 8

typedef _Float16 half_t;
typedef _Float16 half8 __attribute__((ext_vector_type(8)));
typedef _Float16 half4v __attribute__((ext_vector_type(4)));
typedef float f32x4 __attribute__((ext_vector_type(4)));
typedef unsigned int u32;

#define MFMA16(A,B,C) __builtin_amdgcn_mfma_f32_16x16x32_f16((A),(B),(C),0,0,0)

// async 16B global->LDS: lds dst = wave-uniform base + lane*16
#define ASYNC_CP16(dst_lds, src_glb) \
    __builtin_amdgcn_global_load_lds( \
        (const __attribute__((address_space(1))) u32*)(const void*)(src_glb), \
        (__attribute__((address_space(3))) u32*)(void*)(dst_lds), 16, 0, 0)

static __device__ __forceinline__ half8 splat8(half_t x) {
    return (half8){x, x, x, x, x, x, x, x};
}

// ---------------------------------------------------------------------------
// T: transpose + fp32->fp16  k,v [bh][n][32] -> [bh][32][n]
// ---------------------------------------------------------------------------
__global__ __launch_bounds__(256)
void t_kernel(const float* __restrict__ kin, const float* __restrict__ vin,
              half_t* __restrict__ kTg, half_t* __restrict__ vTg)
{
    const int nb = blockIdx.x;     // 16 blocks of 256 n
    const int bh = blockIdx.y;
    const int t  = threadIdx.x;
    __shared__ __align__(16) half_t tile[32 * 272];
    const size_t inbase = ((size_t)bh * NTOK + nb * 256) * 32;

    for (int pass = 0; pass < 2; ++pass) {
        const float* src = pass ? vin : kin;
        half_t* dstg     = pass ? vTg : kTg;
        if (pass) __syncthreads();
        const float4* s4 = (const float4*)(src + inbase);
        #pragma unroll
        for (int r = 0; r < 8; ++r) {
            int f4 = t + 256 * r;
            int n = f4 >> 3, d4 = f4 & 7;
            float4 vv = s4[f4];
            int nn = n ^ ((d4 & 7) << 3);
            int d0 = d4 * 4;
            tile[(d0 + 0) * 272 + nn] = (half_t)vv.x;
            tile[(d0 + 1) * 272 + nn] = (half_t)vv.y;
            tile[(d0 + 2) * 272 + nn] = (half_t)vv.z;
            tile[(d0 + 3) * 272 + nn] = (half_t)vv.w;
        }
        __syncthreads();
        #pragma unroll
        for (int cc = 0; cc < 4; ++cc) {
            int lin = t + 256 * cc;
            int d = lin >> 5, ch = lin & 31;
            int sw = (d >> 2) & 7;
            half8 val = *(const half8*)&tile[d * 272 + ((ch ^ sw) << 3)];
            *(half8*)&dstg[((size_t)bh * 32 + d) * NTOK + nb * 256 + ch * 8] = val;
        }
    }
}

// ---------------------------------------------------------------------------
// A: G[p][e] = sum_n phi(k_n)[p] * [v_n | 1][e]  via f16 MFMA.
// Merged feature grid: blockIdx.y=0 -> features 0..575 (9 m-tiles/wave),
// y=1 -> 576..1087 (8 m-tiles/wave). Per-tile fragment select:
//   pm<32: linear (af=kj half), pm==1056: const row, else 0.5*k_i (*) kj.
// Double-buffered global_load_lds staging, ONE barrier per stage:
//   copy(st+1) issued right after barrier(st) -> overlaps compute(st).
// ---------------------------------------------------------------------------
template<int NMT>
__device__ __forceinline__ void a_body(
    const half_t* __restrict__ kTg, const half_t* __restrict__ vTg,
    half_t* __restrict__ P, int Kc, int bh, int kc, int pw,
    int t, int w, int l16, int quad, half_t* kT0, half_t* vT0)
{
    const half8 h05 = splat8((half_t)0.5f);
    f32x4 acc[NMT][3];
    #pragma unroll
    for (int m = 0; m < NMT; ++m)
        #pragma unroll
        for (int e = 0; e < 3; ++e)
            acc[m][e] = (f32x4){0.f, 0.f, 0.f, 0.f};

    const size_t gbase = (size_t)bh * 32 * NTOK;
    const int nPer = NTOK / Kc;
    const int nStages = nPer >> 7;

    // staging source map (incorporates the chunk-XOR LDS swizzle)
    const int c0 = t,        r0 = c0 >> 4, p0s = (c0 & 15) ^ (r0 & 15);
    const int c1 = 256 + t,  r1 = c1 >> 4, p1s = (c1 & 15) ^ (r1 & 15);

    auto issue = [&](int buf, int nbase) {
        const half_t* gk0 = kTg + gbase + (size_t)r0 * NTOK + nbase + p0s * 8;
        const half_t* gk1 = kTg + gbase + (size_t)r1 * NTOK + nbase + p1s * 8;
        const half_t* gv0 = vTg + gbase + (size_t)r0 * NTOK + nbase + p0s * 8;
        const half_t* gv1 = vTg + gbase + (size_t)r1 * NTOK + nbase + p1s * 8;
        half_t* kb = kT0 + buf * 4096;
        half_t* vb = vT0 + buf * 4096;
        ASYNC_CP16(kb + (size_t)w * 512,        gk0);
        ASYNC_CP16(kb + 2048 + (size_t)w * 512, gk1);
        ASYNC_CP16(vb + (size_t)w * 512,        gv0);
        ASYNC_CP16(vb + 2048 + (size_t)w * 512, gv1);
    };

    issue(0, kc * nPer);

    for (int st = 0; st < nStages; ++st) {
        const int cur = st & 1;
        __syncthreads();   // drains copy(cur); all waves done with buf cur^1
        if (st + 1 < nStages) issue(cur ^ 1, kc * nPer + (st + 1) * 128);
        const half_t* kb = kT0 + cur * 4096;
        const half_t* vb = vT0 + cur * 4096;
        #pragma unroll
        for (int kk = 0; kk < 4; ++kk) {
            const int c = kk * 4 + quad;
            const int shL = ((c ^ l16) << 3);
            half8 kj0 = *(const half8*)&kb[l16 * 128 + shL];
            half8 kj1 = *(const half8*)&kb[(l16 + 16) * 128 + shL];
            half8 bf0 = *(const half8*)&vb[l16 * 128 + shL];
            half8 bf1 = *(const half8*)&vb[(l16 + 16) * 128 + shL];
            half_t onec = (l16 == 0) ? (half_t)1 : (half_t)0;
            half8 bf2 = {onec, onec, onec, onec, onec, onec, onec, onec};
            #pragma unroll
            for (int mt = 0; mt < NMT; ++mt) {
                const int pm = pw + mt * 16;
                half8 af;
                if (pm < 32) {
                    af = pm ? kj1 : kj0;
                } else if (pm == 1056) {
                    af = bf2;                       // const feature row
                } else if (pm > 1056) {
                    continue;                       // pad tiles
                } else {
                    const int i = (pm - 32) >> 5;
                    const int j0 = (pm - 32) & 31;
                    half8 ki = *(const half8*)&kb[i * 128 + ((c ^ (i & 15)) << 3)];
                    ki = ki * h05;
                    af = ki * (j0 ? kj1 : kj0);
                }
                acc[mt][0] = MFMA16(af, bf0, acc[mt][0]);
                acc[mt][1] = MFMA16(af, bf1, acc[mt][1]);
                acc[mt][2] = MFMA16(af, bf2, acc[mt][2]);
            }
        }
    }

    half_t* Pb = P + ((size_t)kc * NBH + bh) * NE * NF;
    #pragma unroll
    for (int mt = 0; mt < NMT; ++mt) {
        int p0 = pw + mt * 16 + quad * 4;
        half4v h0 = {(half_t)acc[mt][0][0], (half_t)acc[mt][0][1],
                     (half_t)acc[mt][0][2], (half_t)acc[mt][0][3]};
        half4v h1 = {(half_t)acc[mt][1][0], (half_t)acc[mt][1][1],
                     (half_t)acc[mt][1][2], (half_t)acc[mt][1][3]};
        *(half4v*)&Pb[(size_t)l16 * NF + p0] = h0;
        *(half4v*)&Pb[(size_t)(l16 + 16) * NF + p0] = h1;
        if (l16 == 0) {
            half4v h2 = {(half_t)acc[mt][2][0], (half_t)acc[mt][2][1],
                         (half_t)acc[mt][2][2], (half_t)acc[mt][2][3]};
            *(half4v*)&Pb[(size_t)32 * NF + p0] = h2;
        }
    }
}

__global__ __launch_bounds__(256, 2)
void a_kernel(const half_t* __restrict__ kTg, const half_t* __restrict__ vTg,
              half_t* __restrict__ P, int Kc)
{
    const int x  = blockIdx.x;
    const int bh = x & (NBH - 1);
    const int kc = x >> 5;
    const int half = blockIdx.y;   // 0: feats 0..575, 1: 576..1087
    const int t = threadIdx.x;
    const int w = t >> 6, lane = t & 63, l16 = lane & 15, quad = lane >> 4;

    __shared__ __align__(16) half_t kT[2 * 4096];
    __shared__ __align__(16) half_t vT[2 * 4096];

    if (half == 0) {
        a_body<9>(kTg, vTg, P, Kc, bh, kc, w * 144, t, w, l16, quad, kT, vT);
    } else {
        a_body<8>(kTg, vTg, P, Kc, bh, kc, 576 + w * 128, t, w, l16, quad, kT, vT);
    }
}

// ---------------------------------------------------------------------------
// AR: sum Kc fp16 partial planes (fp32 accum) -> GtF in MFMA-B-FRAGMENT order:
//   GtF[bh][kt(34)][rr(3)][lane=quad*16+l16][j(8)]
// ---------------------------------------------------------------------------
__global__ __launch_bounds__(256)
void ar_kernel(const half_t* __restrict__ P, half_t* __restrict__ GtF, int Kc)
{
    const int NP8 = NBH * NE * NF / 8;   // 143616
    const int idx = blockIdx.x * 256 + threadIdx.x;
    if (idx >= NP8) return;
    float s[8] = {0.f, 0.f, 0.f, 0.f, 0.f, 0.f, 0.f, 0.f};
    for (int c = 0; c < Kc; ++c) {
        half8 h = *(const half8*)&P[(size_t)c * (NBH * NE * NF) + (size_t)idx * 8];
        #pragma unroll
        for (int j = 0; j < 8; ++j) s[j] += (float)h[j];
    }
    half8 o;
    #pragma unroll
    for (int j = 0; j < 8; ++j) o[j] = (half_t)s[j];
    int row = idx / 136;                 // NF/8
    int p8 = idx - row * 136;
    int e = row % 33, bhh = row / 33;
    int kt = p8 >> 2, quad = p8 & 3;
    int rr = e >> 4, l16 = e & 15;       // e==32 -> rr=2, l16=0
    size_t dst8 = (size_t)bhh * (GTF_BH / 8)
                + (size_t)(kt * 3 + rr) * 64 + quad * 16 + l16;
    *(half8*)&GtF[dst8 * 8] = o;
}

// ---------------------------------------------------------------------------
// B: out[n][e] = (phi(q_n).G[:,e]) / (phi(q_n).G[:,32]) via f16 MFMA.
// GtF fragments are lane-dense (1KB/wave/load), depth-3 register ring.
// kt=33 carries the const feature (af = e_0 on quad 0).
// ---------------------------------------------------------------------------
__global__ __launch_bounds__(256)
void b_kernel(const float* __restrict__ qin, const half_t* __restrict__ GtF,
              float* __restrict__ out)
{
    const int bh = blockIdx.x, mbq = blockIdx.y;   // 32 x 16
    const int t = threadIdx.x, w = t >> 6, lane = t & 63;
    const int l16 = lane & 15, quad = lane >> 4;
    __shared__ __align__(16) half_t qs[256 * 40];
    __shared__ __align__(16) half_t qsP[32 * 272];  // [i][w][l16][mt]
    __shared__ float denl[256];
    const size_t nbase = (size_t)bh * NTOK + mbq * 256;

    const float4* q4 = (const float4*)(qin + nbase * 32);
    #pragma unroll
    for (int r = 0; r < 8; ++r) {
        int f4 = t + 256 * r, n = f4 >> 3, d4 = f4 & 7;
        float4 vv = q4[f4];
        half4v h = {(half_t)vv.x, (half_t)vv.y, (half_t)vv.z, (half_t)vv.w};
        *(half4v*)&qs[n * 40 + d4 * 4] = h;
        int pb = (n >> 6) * 64 + (n & 15) * 4 + ((n >> 4) & 3);
        qsP[(4 * d4 + 0) * 272 + pb] = h[0];
        qsP[(4 * d4 + 1) * 272 + pb] = h[1];
        qsP[(4 * d4 + 2) * 272 + pb] = h[2];
        qsP[(4 * d4 + 3) * 272 + pb] = h[3];
    }
    __syncthreads();

    const int rbase = w * 64;
    half8 vq[4];
    #pragma unroll
    for (int mt = 0; mt < 4; ++mt)
        vq[mt] = *(const half8*)&qs[(rbase + mt * 16 + l16) * 40 + quad * 8];

    f32x4 acc[3][4];
    #pragma unroll
    for (int a = 0; a < 3; ++a)
        #pragma unroll
        for (int b = 0; b < 4; ++b)
            acc[a][b] = (f32x4){0.f, 0.f, 0.f, 0.f};

    const half_t* Gb = GtF + (size_t)bh * GTF_BH + (size_t)lane * 8;
    const int sOff = w * 64 + l16 * 4;

#define LDF(kt, B) do { \
    _Pragma("unroll") \
    for (int rr = 0; rr < 3; ++rr) \
        (B)[rr] = *(const half8*)&Gb[(size_t)(((kt) * 3 + rr) * 64) * 8]; \
} while (0)

    half8 B0[3], B1[3], B2[3], B3[3];
    LDF(0, B0); LDF(1, B1); LDF(2, B2);

    // kt = 0: linear features, af = vq
    {
        LDF(3, B3);
        #pragma unroll
        for (int mt = 0; mt < 4; ++mt) {
            acc[0][mt] = MFMA16(vq[mt], B0[0], acc[0][mt]);
            acc[1][mt] = MFMA16(vq[mt], B0[1], acc[1][mt]);
            acc[2][mt] = MFMA16(vq[mt], B0[2], acc[2][mt]);
        }
        #pragma unroll
        for (int rr = 0; rr < 3; ++rr) { B0[rr] = B1[rr]; B1[rr] = B2[rr]; B2[rr] = B3[rr]; }
    }
    // kt = 1..32: quadratic features, af = q_i * vq
    #pragma unroll 1
    for (int kt = 1; kt <= 32; ++kt) {
        const int ktp = (kt + 3 <= 33) ? kt + 3 : 33;
        LDF(ktp, B3);
        half4v sv = *(const half4v*)&qsP[(kt - 1) * 272 + sOff];
        half8 af[4];
        #pragma unroll
        for (int mt = 0; mt < 4; ++mt)
            af[mt] = vq[mt] * splat8(sv[mt]);
        #pragma unroll
        for (int mt = 0; mt < 4; ++mt) {
            acc[0][mt] = MFMA16(af[mt], B0[0], acc[0][mt]);
            acc[1][mt] = MFMA16(af[mt], B0[1], acc[1][mt]);
            acc[2][mt] = MFMA16(af[mt], B0[2], acc[2][mt]);
        }
        #pragma unroll
        for (int rr = 0; rr < 3; ++rr) { B0[rr] = B1[rr]; B1[rr] = B2[rr]; B2[rr] = B3[rr]; }
    }
    // kt = 33: const feature at p=1056: af = e0 on quad 0
    {
        half8 cf = {};
        if (quad == 0) cf[0] = (half_t)1;
        #pragma unroll
        for (int mt = 0; mt < 4; ++mt) {
            acc[0][mt] = MFMA16(cf, B0[0], acc[0][mt]);
            acc[1][mt] = MFMA16(cf, B0[1], acc[1][mt]);
            acc[2][mt] = MFMA16(cf, B0[2], acc[2][mt]);
        }
    }
#undef LDF

    // broadcast den (col 32 lives in l16==0 lanes of acc[2]) via LDS
    if (l16 == 0) {
        #pragma unroll
        for (int mt = 0; mt < 4; ++mt)
            #pragma unroll
            for (int r = 0; r < 4; ++r)
                denl[rbase + mt * 16 + quad * 4 + r] = acc[2][mt][r];
    }
    __syncthreads();
    #pragma unroll
    for (int mt = 0; mt < 4; ++mt) {
        float inv[4];
        #pragma unroll
        for (int r = 0; r < 4; ++r)
            inv[r] = __builtin_amdgcn_rcpf(denl[rbase + mt * 16 + quad * 4 + r]);
        #pragma unroll
        for (int r = 0; r < 4; ++r) {
            size_t ro = (nbase + rbase + mt * 16 + quad * 4 + r) * 32;
            out[ro + l16] = acc[0][mt][r] * inv[r];
            out[ro + l16 + 16] = acc[1][mt][r] * inv[r];
        }
    }
}

// ---------------------------------------------------------------------------
extern "C" void kernel_launch(void* const* d_in, const int* in_sizes, int n_in,
                              void* d_out, int out_size, void* d_ws, size_t ws_size,
                              hipStream_t stream)
{
    const float* q = (const float*)d_in[0];
    const float* k = (const float*)d_in[1];
    const float* v = (const float*)d_in[2];
    float* out = (float*)d_out;

    const size_t planeBytes = (size_t)NBH * NE * NF * 2;   // fp16: 2,297,856
    const size_t ktBytes = (size_t)NBH * 32 * NTOK * 2;    // 8,388,608
    const size_t gtBytes = (size_t)NBH * GTF_BH * 2;       // 3,342,336
    int Kc = 8;
    while (Kc > 1 && ((size_t)Kc * planeBytes + 2 * ktBytes + gtBytes) > ws_size)
        Kc >>= 1;

    half_t* P = (half_t*)d_ws;
    half_t* kTg = (half_t*)((char*)d_ws + (size_t)Kc * planeBytes);
    half_t* vTg = kTg + (size_t)NBH * 32 * NTOK;
    half_t* GtF = vTg + (size_t)NBH * 32 * NTOK;

    t_kernel<<<dim3(16, NBH), 256, 0, stream>>>(k, v, kTg, vTg);
    a_kernel<<<dim3(Kc * NBH, 2), 256, 0, stream>>>(kTg, vTg, P, Kc);
    ar_kernel<<<561, 256, 0, stream>>>(P, GtF, Kc);
    b_kernel<<<dim3(NBH, 16), 256, 0, stream>>>(q, GtF, out);
}